// Round 5
// baseline (545.556 us; speedup 1.0000x reference)
//
#include <hip/hip_runtime.h>
#include <math.h>

#define NB 8
#define NSP 16384   // 128*128
#define NHEADS 6
#define BT ((long)NB * NSP)   // 131072 pixels total

typedef __attribute__((ext_vector_type(8))) short bf8_t;   // 8 bf16 (4 VGPR)
typedef __attribute__((ext_vector_type(4))) float f4_t;    // MFMA accumulator
typedef unsigned short u16;

#define MFMA(A,B,C) __builtin_amdgcn_mfma_f32_16x16x32_bf16((A),(B),(C),0,0,0)

__device__ __forceinline__ u16 f2b(float f) {  // fp32 -> bf16 RNE
  union { float f; unsigned u; } v; v.f = f;
  unsigned r = v.u + 0x7FFFu + ((v.u >> 16) & 1u);
  return (u16)(r >> 16);
}
__device__ __forceinline__ float b2f(u16 h) {
  union { unsigned u; float f; } v; v.u = ((unsigned)h) << 16; return v.f;
}

// All activation tensors are chunk-major: [g8 chunk][B*N pixels][8 ch] bf16.
// xb/yb/qL/kL/v: 12 chunks. fin (fuse input, 192 ch): 24 chunks
//   (gf 0..11 = kv hi channels 96..191, gf 12..23 = qv hi channels 96..191).

// ============ pack weights to bf16 (+ fuse-weight permutation) ============
// wfA slot kc = c6*9 + tap (tap-INNER iteration order in fuse_k)
__global__ __launch_bounds__(256)
void pack_w_k(const float* __restrict__ wqv, const float* __restrict__ wkv,
              const float* __restrict__ wpos, const float* __restrict__ wfuse,
              u16* __restrict__ wqv_b, u16* __restrict__ wkv_b,
              u16* __restrict__ wpos_b, u16* __restrict__ wfA) {
  int i = blockIdx.x * 256 + threadIdx.x;
  if (i < 18432) { wqv_b[i] = f2b(wqv[i]); wkv_b[i] = f2b(wkv[i]); }
  if (i < 36864) wpos_b[i] = f2b(wpos[i]);
  if (i < 165888) {
    int kl = i & 31; int rest = i >> 5;
    int oc = rest % 96, kc = rest / 96;
    int c6 = kc / 9, tap = kc % 9;
    int icf = c6 * 32 + kl;
    wfA[i] = f2b(wfuse[(oc * 192 + icf) * 9 + tap]);
  }
}

// ============ transpose-cast x,y: (B,96,N) fp32 -> chunk-major bf16 ============
__global__ __launch_bounds__(256)
void tcast_k(const float* __restrict__ x, const float* __restrict__ y,
             u16* __restrict__ xb, u16* __restrict__ yb) {
  const float* src = blockIdx.y ? y : x;
  u16* dst = blockIdx.y ? yb : xb;
  int t = threadIdx.x;
  long n  = (long)blockIdx.x * 64 + (t & 63);
  long b  = n >> 14; long ni = n & 16383;
  int c8b = t >> 6;                 // 0..3
  for (int i = 0; i < 3; ++i) {
    int c8 = c8b + i * 4;           // 0..11
    bf8_t pk;
#pragma unroll
    for (int j = 0; j < 8; ++j)
      pk[j] = (short)f2b(src[(b * 96 + c8 * 8 + j) * NSP + ni]);
    *(bf8_t*)(dst + ((long)c8 * BT + n) * 8) = pk;
  }
}

// ============ conv1x1 MFMA: 192oc x 64n tile; in/out chunk-major ============
__global__ __launch_bounds__(256)
void conv1x1_k(const u16* __restrict__ Bx, const u16* __restrict__ A,
               u16* __restrict__ out) {
  int t = threadIdx.x, w = t >> 6, lane = t & 63;
  int q = lane >> 4, l15 = lane & 15;
  long n0 = (long)blockIdx.x * 64;
  f4_t acc[3][4] = {};
#pragma unroll
  for (int kc = 0; kc < 3; ++kc) {
    bf8_t af[3], bfr[4];
#pragma unroll
    for (int mf = 0; mf < 3; ++mf)
      af[mf] = *(const bf8_t*)(A + (w * 48 + mf * 16 + l15) * 96 + kc * 32 + q * 8);
#pragma unroll
    for (int nf = 0; nf < 4; ++nf)
      bfr[nf] = *(const bf8_t*)(Bx + ((long)(kc * 4 + q) * BT + n0 + nf * 16 + l15) * 8);
#pragma unroll
    for (int mf = 0; mf < 3; ++mf)
#pragma unroll
      for (int nf = 0; nf < 4; ++nf)
        acc[mf][nf] = MFMA(af[mf], bfr[nf], acc[mf][nf]);
  }
#pragma unroll
  for (int mf = 0; mf < 3; ++mf)
#pragma unroll
    for (int nf = 0; nf < 4; ++nf) {
      union { u16 us[4]; uint2 v; } pk;
#pragma unroll
      for (int r = 0; r < 4; ++r) pk.us[r] = f2b(acc[mf][nf][r]);
      long n = n0 + nf * 16 + l15;
      int g = w * 6 + mf * 2 + (q >> 1);     // oc chunk
      *(uint2*)(out + ((long)g * BT + n) * 8 + (q & 1) * 4) = pk.v;
    }
}

// ============ depthwise 3x3, chunk-major: wave = one g, full row, 2px/lane ============
__global__ __launch_bounds__(256)
void dw_k(const u16* __restrict__ qv0, const u16* __restrict__ kv0,
          const float* __restrict__ wqvd, const float* __restrict__ wkvd,
          u16* __restrict__ qL, u16* __restrict__ kL, u16* __restrict__ fin) {
  int t = threadIdx.x;
  int sel = blockIdx.y;
  int bx = blockIdx.x;              // 0..6143
  int gq = bx % 6;                  // g-quad
  int rowid = bx / 6;               // 0..1023
  long b = rowid >> 7; int r = rowid & 127;
  int wv = __builtin_amdgcn_readfirstlane(t >> 6);
  int g = gq * 4 + wv;              // 0..23, wave-uniform
  int l = t & 63;
  int c0 = l * 2;                   // first of 2 px

  const u16* src  = sel ? kv0 : qv0;
  const float* wd = sel ? wkvd : wqvd;

  float wgt[8][9];
#pragma unroll
  for (int cc = 0; cc < 8; ++cc)
#pragma unroll
    for (int tp = 0; tp < 9; ++tp)
      wgt[cc][tp] = wd[g * 72 + cc * 9 + tp];

  const u16* sg = src + (long)g * BT * 8;   // chunk base
  float acc[2][8] = {};
#pragma unroll
  for (int dy = -1; dy <= 1; ++dy) {
    int rr = r + dy;
    if ((unsigned)rr >= 128u) continue;     // block-uniform
    long nb = (b << 14) + ((long)rr << 7);
    float xq[4][8];
#pragma unroll
    for (int j = 0; j < 4; ++j) {
      int col = c0 - 1 + j;
      uint4 cv = make_uint4(0u, 0u, 0u, 0u);
      if ((unsigned)col < 128u)
        cv = *(const uint4*)(sg + (nb + col) * 8);
      const unsigned* cu = (const unsigned*)&cv;
#pragma unroll
      for (int k = 0; k < 4; ++k) {
        union { unsigned u; float f; } lo, hi;
        lo.u = cu[k] << 16; hi.u = cu[k] & 0xFFFF0000u;
        xq[j][2 * k] = lo.f; xq[j][2 * k + 1] = hi.f;
      }
    }
#pragma unroll
    for (int dx = 0; dx < 3; ++dx) {
      int tp = (dy + 1) * 3 + dx;
#pragma unroll
      for (int px = 0; px < 2; ++px)
#pragma unroll
        for (int cc = 0; cc < 8; ++cc)
          acc[px][cc] += wgt[cc][tp] * xq[px + dx][cc];
    }
  }
  u16* dst; long gi;
  if (g < 12) { dst = sel ? kL : qL; gi = g; }
  else        { dst = fin; gi = sel ? (g - 12) : g; }  // kv hi -> gf 0..11, qv hi -> gf 12..23
  u16* dp = dst + (gi * BT + (b << 14) + ((long)r << 7) + c0) * 8;
#pragma unroll
  for (int px = 0; px < 2; ++px) {
    union { u16 us[8]; uint4 v; } pk;
#pragma unroll
    for (int cc = 0; cc < 8; ++cc) pk.us[cc] = f2b(acc[px][cc]);
    *(uint4*)(dp + px * 8) = pk.v;
  }
}

// ============ fuse 3x3 implicit GEMM: v = Wf(96x1728)*im2col + bias ============
// Barrier-free: A-fragments read directly from global (coalesced 1KB/wave,
// L2-resident); no LDS, no __syncthreads in the K-loop.
__global__ __launch_bounds__(256)
void fuse_k(const u16* __restrict__ fin, const u16* __restrict__ wfA,
            const float* __restrict__ bfuse, u16* __restrict__ vout) {
  int t = threadIdx.x, w = t >> 6, lane = t & 63;
  int q = lane >> 4, l15 = lane & 15;
  int bid = (int)blockIdx.x;
  bid = (bid & 7) * 128 + (bid >> 3);     // XCD swizzle (1024 blocks)
  long n0 = (long)bid * 128;
  long b = n0 >> 14; int nimg0 = (int)(n0 & 16383);

  f4_t acc[6][2];
#pragma unroll
  for (int mf = 0; mf < 6; ++mf) {
#pragma unroll
    for (int rg = 0; rg < 4; ++rg) {
      float bv = bfuse[mf * 16 + q * 4 + rg];
      acc[mf][0][rg] = bv; acc[mf][1][rg] = bv;
    }
  }
  int ni_[2], r_[2], pw_[2];
#pragma unroll
  for (int nf = 0; nf < 2; ++nf) {
    ni_[nf] = nimg0 + w * 32 + nf * 16 + l15;
    r_[nf] = ni_[nf] >> 7; pw_[nf] = ni_[nf] & 127;
  }
  const u16* wl = wfA + l15 * 32 + q * 8;   // per-lane weight base

  for (int kc = 0; kc < 54; ++kc) {
    int c6 = kc / 9, tap = kc % 9;
    int dy = tap / 3 - 1, dx = tap % 3 - 1;
    const u16* src = fin + (long)(c6 * 4 + q) * BT * 8;
    bf8_t bfr[2];
#pragma unroll
    for (int nf = 0; nf < 2; ++nf) {
      bf8_t v = {0,0,0,0,0,0,0,0};
      int rr = r_[nf] + dy, cc = pw_[nf] + dx;
      if ((unsigned)rr < 128u && (unsigned)cc < 128u)
        v = *(const bf8_t*)(src + ((b << 14) + (long)ni_[nf] + dy * 128 + dx) * 8);
      bfr[nf] = v;
    }
    const u16* wsl = wl + kc * 3072;
    bf8_t af[6];
#pragma unroll
    for (int mf = 0; mf < 6; ++mf)
      af[mf] = *(const bf8_t*)(wsl + mf * 512);
#pragma unroll
    for (int mf = 0; mf < 6; ++mf) {
      acc[mf][0] = MFMA(af[mf], bfr[0], acc[mf][0]);
      acc[mf][1] = MFMA(af[mf], bfr[1], acc[mf][1]);
    }
  }
#pragma unroll
  for (int mf = 0; mf < 6; ++mf)
#pragma unroll
    for (int nf = 0; nf < 2; ++nf) {
      union { u16 us[4]; uint2 v; } pk;
#pragma unroll
      for (int rg = 0; rg < 4; ++rg) pk.us[rg] = f2b(acc[mf][nf][rg]);
      long n = n0 + w * 32 + nf * 16 + l15;
      int gg = mf * 2 + (q >> 1);
      *(uint2*)(vout + ((long)gg * BT + n) * 8 + (q & 1) * 4) = pk.v;
    }
}

// ============ per-channel raw sum-of-squares (lo 96 ch), n-split + atomics ============
__global__ __launch_bounds__(256)
void ssq_k(const u16* __restrict__ qL, const u16* __restrict__ kL,
           float* __restrict__ ssq) {
  int c8 = blockIdx.x;
  int b = blockIdx.y >> 1, z = blockIdx.y & 1;
  const u16* src = (z ? kL : qL) + ((long)c8 * BT + (b << 14)) * 8;
  float ss[8] = {};
  int n0 = blockIdx.z * 4096, nend = n0 + 4096;
  for (int n = n0 + threadIdx.x; n < nend; n += 256) {
    bf8_t v = *(const bf8_t*)(src + (long)n * 8);
#pragma unroll
    for (int j = 0; j < 8; ++j) { float f = b2f((u16)v[j]); ss[j] += f * f; }
  }
#pragma unroll
  for (int off = 32; off; off >>= 1)
#pragma unroll
    for (int j = 0; j < 8; ++j) ss[j] += __shfl_down(ss[j], off);
  __shared__ float red[4][8];
  int lane = threadIdx.x & 63, wv = threadIdx.x >> 6;
  if (!lane)
#pragma unroll
    for (int j = 0; j < 8; ++j) red[wv][j] = ss[j];
  __syncthreads();
  if (threadIdx.x < 8) {
    int j = threadIdx.x;
    float tot = red[0][j] + red[1][j] + red[2][j] + red[3][j];
    atomicAdd(&ssq[(z * NB + b) * 96 + c8 * 8 + j], tot);
  }
}

// ============ QK^T: logits[b,h,c,d] = sum_n q[n][h16+c] k[n][h16+d] (raw) ============
__global__ __launch_bounds__(256)
void qk_k(const u16* __restrict__ qL, const u16* __restrict__ kL,
          float* __restrict__ logits) {
  int s = blockIdx.x, h = blockIdx.y, b = blockIdx.z;
  int t = threadIdx.x, c = t >> 4, d = t & 15;
  __shared__ u16 Qs[64 * 16], Ks[64 * 16];
  float acc = 0.f;
  int p = t >> 2, c4 = (t & 3) * 4;
  int ch2 = 2 * h + (c4 >> 3), e = c4 & 7;
  long cb = (long)ch2 * BT + (b << 14) + s * 512;
  for (int it = 0; it < 8; ++it) {
    __syncthreads();
    long a = (cb + it * 64 + p) * 8 + e;
    *(uint2*)(&Qs[p * 16 + c4]) = *(const uint2*)(qL + a);
    *(uint2*)(&Ks[p * 16 + c4]) = *(const uint2*)(kL + a);
    __syncthreads();
#pragma unroll 8
    for (int pp = 0; pp < 64; ++pp)
      acc += b2f(Qs[pp * 16 + c]) * b2f(Ks[pp * 16 + d]);
  }
  atomicAdd(&logits[((b * NHEADS + h) * 16 + c) * 16 + d], acc);
}

// ============ softmax with norm (from raw ssq) + temperature scaling ============
__global__ __launch_bounds__(256)
void softmax_k(const float* __restrict__ logits, const float* __restrict__ ssq,
               const float* __restrict__ temp, float* __restrict__ attn) {
  int t0 = blockIdx.x * 256 + threadIdx.x;
  if (t0 >= NB * 96) return;
  int b = t0 / 96, c96 = t0 % 96;
  int h = c96 >> 4, c = c96 & 15;
  float iq = 1.f / fmaxf(sqrtf(ssq[b * 96 + c96]), 1e-12f);
  float tp = temp[h];
  const float* lp = logits + ((b * NHEADS + h) * 16 + c) * 16;
  const float* sk = ssq + NB * 96 + b * 96 + h * 16;
  float s[16], mx = -3.4e38f;
#pragma unroll
  for (int d = 0; d < 16; ++d) {
    float ik = 1.f / fmaxf(sqrtf(sk[d]), 1e-12f);
    float l = lp[d] * iq * ik * tp;
    s[d] = l; mx = fmaxf(mx, l);
  }
  float sum = 0.f;
#pragma unroll
  for (int d = 0; d < 16; ++d) { s[d] = __expf(s[d] - mx); sum += s[d]; }
  float rr = 1.f / sum;
  float* ap = attn + ((b * NHEADS + h) * 16 + c) * 16;
#pragma unroll
  for (int d = 0; d < 16; ++d) ap[d] = s[d] * rr;
}

// ============ W'[b] = Wproj * blockdiag(attn_b): (192 x 96) bf16 per batch ============
__global__ __launch_bounds__(256)
void wattn_k(const float* __restrict__ wproj, const float* __restrict__ attn,
             u16* __restrict__ Wp) {
  int b = blockIdx.x, t = threadIdx.x;
  __shared__ float at[1536];
  for (int i = t; i < 1536; i += 256) at[i] = attn[b * 1536 + i];
  __syncthreads();
  for (int i = t; i < 192 * 96; i += 256) {
    int oc = i / 96, e = i % 96;
    int h = e >> 4, d = e & 15;
    float s = 0.f;
#pragma unroll
    for (int c = 0; c < 16; ++c)
      s += wproj[oc * 96 + h * 16 + c] * at[(h * 16 + c) * 16 + d];
    Wp[(long)b * 18432 + i] = f2b(s);
  }
}

// ============ final: out = [W'_b | Wpos] * [v; x; y]; NCHW fp32 out ============
__global__ __launch_bounds__(256)
void final_k(const u16* __restrict__ Wp, const u16* __restrict__ wpos_b,
             const u16* __restrict__ v, const u16* __restrict__ xb,
             const u16* __restrict__ yb, float* __restrict__ out) {
  int t = threadIdx.x, w = t >> 6, lane = t & 63;
  int q = lane >> 4, l15 = lane & 15;
  long n0 = (long)blockIdx.x * 64;
  long b = n0 >> 14; int ni0 = (int)(n0 & 16383);
  f4_t acc[3][4] = {};
  const u16* Ab0 = Wp + b * 18432;
#pragma unroll
  for (int kc = 0; kc < 9; ++kc) {
    const u16 *Asrc, *Bsrc; int astr, koff, gB;
    if (kc < 3)      { Asrc = Ab0;    astr = 96;  koff = kc * 32;            Bsrc = v;  gB = kc * 4 + q; }
    else if (kc < 6) { Asrc = wpos_b; astr = 192; koff = (kc - 3) * 32;      Bsrc = xb; gB = (kc - 3) * 4 + q; }
    else             { Asrc = wpos_b; astr = 192; koff = 96 + (kc - 6) * 32; Bsrc = yb; gB = (kc - 6) * 4 + q; }
    bf8_t af[3], bfr[4];
#pragma unroll
    for (int mf = 0; mf < 3; ++mf)
      af[mf] = *(const bf8_t*)(Asrc + (w * 48 + mf * 16 + l15) * astr + koff + q * 8);
#pragma unroll
    for (int nf = 0; nf < 4; ++nf)
      bfr[nf] = *(const bf8_t*)(Bsrc + ((long)gB * BT + n0 + nf * 16 + l15) * 8);
#pragma unroll
    for (int mf = 0; mf < 3; ++mf)
#pragma unroll
      for (int nf = 0; nf < 4; ++nf)
        acc[mf][nf] = MFMA(af[mf], bfr[nf], acc[mf][nf]);
  }
#pragma unroll
  for (int mf = 0; mf < 3; ++mf)
#pragma unroll
    for (int nf = 0; nf < 4; ++nf)
#pragma unroll
      for (int rg = 0; rg < 4; ++rg) {
        int oc = w * 48 + mf * 16 + q * 4 + rg;
        out[(b * 192 + oc) * (long)NSP + ni0 + nf * 16 + l15] = acc[mf][nf][rg];
      }
}

extern "C" void kernel_launch(void* const* d_in, const int* in_sizes, int n_in,
                              void* d_out, int out_size, void* d_ws, size_t ws_size,
                              hipStream_t stream) {
  const float* x     = (const float*)d_in[0];
  const float* y     = (const float*)d_in[1];
  const float* wpos  = (const float*)d_in[2];
  const float* wqv   = (const float*)d_in[3];
  const float* wqvd  = (const float*)d_in[4];
  const float* wkv   = (const float*)d_in[5];
  const float* wkvd  = (const float*)d_in[6];
  const float* wproj = (const float*)d_in[7];
  const float* wfuse = (const float*)d_in[8];
  const float* bfuse = (const float*)d_in[9];
  const float* temp  = (const float*)d_in[10];
  float* out = (float*)d_out;
  char*  ws  = (char*)d_ws;

  u16*   xb     = (u16*)(ws);                  // [12][BT][8]
  u16*   yb     = (u16*)(ws + 25165824);       // [12][BT][8]
  u16*   qL     = (u16*)(ws + 50331648);       // q lo-96 [12][BT][8]
  u16*   kL     = (u16*)(ws + 75497472);       // k lo-96 [12][BT][8]
  u16*   fin    = (u16*)(ws + 100663296);      // fuse in [24][BT][8]
  u16*   v      = (u16*)(ws + 150994944);      // [12][BT][8]
  u16*   wqv_b  = (u16*)(ws + 176160768);
  u16*   wkv_b  = (u16*)(ws + 176197632);
  u16*   wpos_b = (u16*)(ws + 176234496);
  u16*   wfA    = (u16*)(ws + 176308224);
  u16*   Wp     = (u16*)(ws + 176640000);
  float* ssq    = (float*)(ws + 176934912);
  float* logits = (float*)(ws + 176941056);
  float* attn   = (float*)(ws + 176990208);

  // d_out doubles as bf16 scratch for the two 1x1-conv outputs (dead after dw)
  u16* qv0 = (u16*)d_out;                       // [24][BT][8]
  u16* kv0 = (u16*)d_out + (size_t)24 * BT * 8; // [24][BT][8]

  dim3 blk(256);
  pack_w_k<<<648, blk, 0, stream>>>(wqv, wkv, wpos, wfuse, wqv_b, wkv_b, wpos_b, wfA);
  tcast_k<<<dim3(2048, 2), blk, 0, stream>>>(x, y, xb, yb);
  conv1x1_k<<<2048, blk, 0, stream>>>(xb, wqv_b, qv0);
  conv1x1_k<<<2048, blk, 0, stream>>>(yb, wkv_b, kv0);
  dw_k<<<dim3(6144, 2), blk, 0, stream>>>(qv0, kv0, wqvd, wkvd, qL, kL, fin);
  hipMemsetAsync(ssq, 0, 6144 + 49152, stream);  // ssq + logits (contiguous)
  fuse_k<<<1024, blk, 0, stream>>>(fin, wfA, bfuse, v);
  ssq_k<<<dim3(12, 16, 4), blk, 0, stream>>>(qL, kL, ssq);
  qk_k<<<dim3(32, NHEADS, NB), blk, 0, stream>>>(qL, kL, logits);
  softmax_k<<<3, blk, 0, stream>>>(logits, ssq, temp, attn);
  wattn_k<<<NB, blk, 0, stream>>>(wproj, attn, Wp);
  final_k<<<2048, blk, 0, stream>>>(Wp, wpos_b, v, xb, yb, out);
}

// Round 6
// 478.766 us; speedup vs baseline: 1.1395x; 1.1395x over previous
//
#include <hip/hip_runtime.h>
#include <math.h>

#define NB 8
#define NSP 16384   // 128*128
#define NHEADS 6
#define BT ((long)NB * NSP)   // 131072 pixels total

typedef __attribute__((ext_vector_type(8))) short bf8_t;   // 8 bf16 (4 VGPR)
typedef __attribute__((ext_vector_type(4))) float f4_t;    // MFMA accumulator
typedef unsigned short u16;

#define MFMA(A,B,C) __builtin_amdgcn_mfma_f32_16x16x32_bf16((A),(B),(C),0,0,0)

__device__ __forceinline__ u16 f2b(float f) {  // fp32 -> bf16 RNE
  union { float f; unsigned u; } v; v.f = f;
  unsigned r = v.u + 0x7FFFu + ((v.u >> 16) & 1u);
  return (u16)(r >> 16);
}
__device__ __forceinline__ float b2f(u16 h) {
  union { unsigned u; float f; } v; v.u = ((unsigned)h) << 16; return v.f;
}

// All activation tensors are chunk-major: [g8 chunk][B*N pixels][8 ch] bf16.
// xb/yb/qL/kL/v: 12 chunks. fin (fuse input, 192 ch): 24 chunks
//   (gf 0..11 = kv hi channels 96..191, gf 12..23 = qv hi channels 96..191).

// ============ pack weights to bf16 (+ fuse-weight permutation) ============
// wfA slot kc = c6*9 + tap (tap-INNER iteration order in fuse_k)
__global__ __launch_bounds__(256)
void pack_w_k(const float* __restrict__ wqv, const float* __restrict__ wkv,
              const float* __restrict__ wpos, const float* __restrict__ wfuse,
              u16* __restrict__ wqv_b, u16* __restrict__ wkv_b,
              u16* __restrict__ wpos_b, u16* __restrict__ wfA) {
  int i = blockIdx.x * 256 + threadIdx.x;
  if (i < 18432) { wqv_b[i] = f2b(wqv[i]); wkv_b[i] = f2b(wkv[i]); }
  if (i < 36864) wpos_b[i] = f2b(wpos[i]);
  if (i < 165888) {
    int kl = i & 31; int rest = i >> 5;
    int oc = rest % 96, kc = rest / 96;
    int c6 = kc / 9, tap = kc % 9;
    int icf = c6 * 32 + kl;
    wfA[i] = f2b(wfuse[(oc * 192 + icf) * 9 + tap]);
  }
}

// ============ transpose-cast x,y: (B,96,N) fp32 -> chunk-major bf16 ============
__global__ __launch_bounds__(256)
void tcast_k(const float* __restrict__ x, const float* __restrict__ y,
             u16* __restrict__ xb, u16* __restrict__ yb) {
  const float* src = blockIdx.y ? y : x;
  u16* dst = blockIdx.y ? yb : xb;
  int t = threadIdx.x;
  long n  = (long)blockIdx.x * 64 + (t & 63);
  long b  = n >> 14; long ni = n & 16383;
  int c8b = t >> 6;                 // 0..3
  for (int i = 0; i < 3; ++i) {
    int c8 = c8b + i * 4;           // 0..11
    bf8_t pk;
#pragma unroll
    for (int j = 0; j < 8; ++j)
      pk[j] = (short)f2b(src[(b * 96 + c8 * 8 + j) * NSP + ni]);
    *(bf8_t*)(dst + ((long)c8 * BT + n) * 8) = pk;
  }
}

// ============ conv1x1 MFMA: 192oc x 64n tile; in/out chunk-major ============
__global__ __launch_bounds__(256)
void conv1x1_k(const u16* __restrict__ Bx, const u16* __restrict__ A,
               u16* __restrict__ out) {
  int t = threadIdx.x, w = t >> 6, lane = t & 63;
  int q = lane >> 4, l15 = lane & 15;
  long n0 = (long)blockIdx.x * 64;
  f4_t acc[3][4] = {};
#pragma unroll
  for (int kc = 0; kc < 3; ++kc) {
    bf8_t af[3], bfr[4];
#pragma unroll
    for (int mf = 0; mf < 3; ++mf)
      af[mf] = *(const bf8_t*)(A + (w * 48 + mf * 16 + l15) * 96 + kc * 32 + q * 8);
#pragma unroll
    for (int nf = 0; nf < 4; ++nf)
      bfr[nf] = *(const bf8_t*)(Bx + ((long)(kc * 4 + q) * BT + n0 + nf * 16 + l15) * 8);
#pragma unroll
    for (int mf = 0; mf < 3; ++mf)
#pragma unroll
      for (int nf = 0; nf < 4; ++nf)
        acc[mf][nf] = MFMA(af[mf], bfr[nf], acc[mf][nf]);
  }
#pragma unroll
  for (int mf = 0; mf < 3; ++mf)
#pragma unroll
    for (int nf = 0; nf < 4; ++nf) {
      union { u16 us[4]; uint2 v; } pk;
#pragma unroll
      for (int r = 0; r < 4; ++r) pk.us[r] = f2b(acc[mf][nf][r]);
      long n = n0 + nf * 16 + l15;
      int g = w * 6 + mf * 2 + (q >> 1);     // oc chunk
      *(uint2*)(out + ((long)g * BT + n) * 8 + (q & 1) * 4) = pk.v;
    }
}

// ============ depthwise 3x3, chunk-major: wave = one g, full row, 2px/lane ============
__global__ __launch_bounds__(256)
void dw_k(const u16* __restrict__ qv0, const u16* __restrict__ kv0,
          const float* __restrict__ wqvd, const float* __restrict__ wkvd,
          u16* __restrict__ qL, u16* __restrict__ kL, u16* __restrict__ fin) {
  int t = threadIdx.x;
  int sel = blockIdx.y;
  int bx = blockIdx.x;              // 0..6143
  int gq = bx % 6;                  // g-quad
  int rowid = bx / 6;               // 0..1023
  long b = rowid >> 7; int r = rowid & 127;
  int wv = __builtin_amdgcn_readfirstlane(t >> 6);
  int g = gq * 4 + wv;              // 0..23, wave-uniform
  int l = t & 63;
  int c0 = l * 2;                   // first of 2 px

  const u16* src  = sel ? kv0 : qv0;
  const float* wd = sel ? wkvd : wqvd;

  float wgt[8][9];
#pragma unroll
  for (int cc = 0; cc < 8; ++cc)
#pragma unroll
    for (int tp = 0; tp < 9; ++tp)
      wgt[cc][tp] = wd[g * 72 + cc * 9 + tp];

  const u16* sg = src + (long)g * BT * 8;   // chunk base
  float acc[2][8] = {};
#pragma unroll
  for (int dy = -1; dy <= 1; ++dy) {
    int rr = r + dy;
    if ((unsigned)rr >= 128u) continue;     // block-uniform
    long nb = (b << 14) + ((long)rr << 7);
    float xq[4][8];
#pragma unroll
    for (int j = 0; j < 4; ++j) {
      int col = c0 - 1 + j;
      uint4 cv = make_uint4(0u, 0u, 0u, 0u);
      if ((unsigned)col < 128u)
        cv = *(const uint4*)(sg + (nb + col) * 8);
      const unsigned* cu = (const unsigned*)&cv;
#pragma unroll
      for (int k = 0; k < 4; ++k) {
        union { unsigned u; float f; } lo, hi;
        lo.u = cu[k] << 16; hi.u = cu[k] & 0xFFFF0000u;
        xq[j][2 * k] = lo.f; xq[j][2 * k + 1] = hi.f;
      }
    }
#pragma unroll
    for (int dx = 0; dx < 3; ++dx) {
      int tp = (dy + 1) * 3 + dx;
#pragma unroll
      for (int px = 0; px < 2; ++px)
#pragma unroll
        for (int cc = 0; cc < 8; ++cc)
          acc[px][cc] += wgt[cc][tp] * xq[px + dx][cc];
    }
  }
  u16* dst; long gi;
  if (g < 12) { dst = sel ? kL : qL; gi = g; }
  else        { dst = fin; gi = sel ? (g - 12) : g; }  // kv hi -> gf 0..11, qv hi -> gf 12..23
  u16* dp = dst + (gi * BT + (b << 14) + ((long)r << 7) + c0) * 8;
#pragma unroll
  for (int px = 0; px < 2; ++px) {
    union { u16 us[8]; uint4 v; } pk;
#pragma unroll
    for (int cc = 0; cc < 8; ++cc) pk.us[cc] = f2b(acc[px][cc]);
    *(uint4*)(dp + px * 8) = pk.v;
  }
}

// ============ fuse 3x3 implicit GEMM: v = Wf(96x1728)*im2col + bias ============
// 512 threads / 8 waves / 256 px per block; 2 weight chunks staged per phase
// (LDS double-buffer, 192 padded rows of 36 u16); one barrier per 2 kc.
__global__ __launch_bounds__(512)
void fuse_k(const u16* __restrict__ fin, const u16* __restrict__ wfA,
            const float* __restrict__ bfuse, u16* __restrict__ vout) {
  __shared__ __align__(16) u16 AL[2][192 * 36];
  int t = threadIdx.x, w = t >> 6, lane = t & 63;
  int q = lane >> 4, l15 = lane & 15;
  int bid = (int)blockIdx.x;
  bid = (bid & 7) * 64 + (bid >> 3);     // XCD swizzle (512 blocks, 1 image/XCD)
  long n0 = (long)bid * 256;
  long b = n0 >> 14; int nimg0 = (int)(n0 & 16383);

  f4_t acc[6][2];
#pragma unroll
  for (int mf = 0; mf < 6; ++mf) {
#pragma unroll
    for (int rg = 0; rg < 4; ++rg) {
      float bv = bfuse[mf * 16 + q * 4 + rg];
      acc[mf][0][rg] = bv; acc[mf][1][rg] = bv;
    }
  }
  int ni_[2], r_[2], pw_[2];
#pragma unroll
  for (int nf = 0; nf < 2; ++nf) {
    ni_[nf] = nimg0 + w * 32 + nf * 16 + l15;
    r_[nf] = ni_[nf] >> 7; pw_[nf] = ni_[nf] & 127;
  }
  // stage chunks 0,1 (768 f4_t; 192 rows of 32 u16 -> padded stride 36)
  for (int i = t; i < 768; i += 512)
    *(f4_t*)(&AL[0][(i >> 2) * 36 + (i & 3) * 8]) = *(const f4_t*)(wfA + i * 8);
  __syncthreads();

  for (int kc2 = 0; kc2 < 27; ++kc2) {
    int cur = kc2 & 1;
    if (kc2 < 26) {
      const u16* srcw = wfA + (kc2 + 1) * 6144;
      for (int i = t; i < 768; i += 512)
        *(f4_t*)(&AL[cur ^ 1][(i >> 2) * 36 + (i & 3) * 8]) = *(const f4_t*)(srcw + i * 8);
    }
#pragma unroll
    for (int h = 0; h < 2; ++h) {
      int kc = kc2 * 2 + h;
      int c6 = kc / 9, tap = kc % 9;
      int dy = tap / 3 - 1, dx = tap % 3 - 1;
      const u16* src = fin + (long)(c6 * 4 + q) * BT * 8;
      bf8_t bfr[2];
#pragma unroll
      for (int nf = 0; nf < 2; ++nf) {
        bf8_t v = {0,0,0,0,0,0,0,0};
        int rr = r_[nf] + dy, cc = pw_[nf] + dx;
        if ((unsigned)rr < 128u && (unsigned)cc < 128u)
          v = *(const bf8_t*)(src + ((b << 14) + (long)ni_[nf] + dy * 128 + dx) * 8);
        bfr[nf] = v;
      }
      bf8_t af[6];
#pragma unroll
      for (int mf = 0; mf < 6; ++mf)
        af[mf] = *(const bf8_t*)(&AL[cur][(h * 96 + mf * 16 + l15) * 36 + q * 8]);
#pragma unroll
      for (int mf = 0; mf < 6; ++mf) {
        acc[mf][0] = MFMA(af[mf], bfr[0], acc[mf][0]);
        acc[mf][1] = MFMA(af[mf], bfr[1], acc[mf][1]);
      }
    }
    __syncthreads();
  }
#pragma unroll
  for (int mf = 0; mf < 6; ++mf)
#pragma unroll
    for (int nf = 0; nf < 2; ++nf) {
      union { u16 us[4]; uint2 v; } pk;
#pragma unroll
      for (int rg = 0; rg < 4; ++rg) pk.us[rg] = f2b(acc[mf][nf][rg]);
      long n = n0 + w * 32 + nf * 16 + l15;
      int gg = mf * 2 + (q >> 1);
      *(uint2*)(vout + ((long)gg * BT + n) * 8 + (q & 1) * 4) = pk.v;
    }
}

// ============ per-channel raw sum-of-squares (lo 96 ch), n-split + atomics ============
__global__ __launch_bounds__(256)
void ssq_k(const u16* __restrict__ qL, const u16* __restrict__ kL,
           float* __restrict__ ssq) {
  int c8 = blockIdx.x;
  int b = blockIdx.y >> 1, z = blockIdx.y & 1;
  const u16* src = (z ? kL : qL) + ((long)c8 * BT + (b << 14)) * 8;
  float ss[8] = {};
  int n0 = blockIdx.z * 4096, nend = n0 + 4096;
  for (int n = n0 + threadIdx.x; n < nend; n += 256) {
    bf8_t v = *(const bf8_t*)(src + (long)n * 8);
#pragma unroll
    for (int j = 0; j < 8; ++j) { float f = b2f((u16)v[j]); ss[j] += f * f; }
  }
#pragma unroll
  for (int off = 32; off; off >>= 1)
#pragma unroll
    for (int j = 0; j < 8; ++j) ss[j] += __shfl_down(ss[j], off);
  __shared__ float red[4][8];
  int lane = threadIdx.x & 63, wv = threadIdx.x >> 6;
  if (!lane)
#pragma unroll
    for (int j = 0; j < 8; ++j) red[wv][j] = ss[j];
  __syncthreads();
  if (threadIdx.x < 8) {
    int j = threadIdx.x;
    float tot = red[0][j] + red[1][j] + red[2][j] + red[3][j];
    atomicAdd(&ssq[(z * NB + b) * 96 + c8 * 8 + j], tot);
  }
}

// ============ QK^T: logits[b,h,c,d] = sum_n q[n][h16+c] k[n][h16+d] (raw) ============
__global__ __launch_bounds__(256)
void qk_k(const u16* __restrict__ qL, const u16* __restrict__ kL,
          float* __restrict__ logits) {
  int s = blockIdx.x, h = blockIdx.y, b = blockIdx.z;
  int t = threadIdx.x, c = t >> 4, d = t & 15;
  __shared__ u16 Qs[64 * 16], Ks[64 * 16];
  float acc = 0.f;
  int p = t >> 2, c4 = (t & 3) * 4;
  int ch2 = 2 * h + (c4 >> 3), e = c4 & 7;
  long cb = (long)ch2 * BT + (b << 14) + s * 512;
  for (int it = 0; it < 8; ++it) {
    __syncthreads();
    long a = (cb + it * 64 + p) * 8 + e;
    *(uint2*)(&Qs[p * 16 + c4]) = *(const uint2*)(qL + a);
    *(uint2*)(&Ks[p * 16 + c4]) = *(const uint2*)(kL + a);
    __syncthreads();
#pragma unroll 8
    for (int pp = 0; pp < 64; ++pp)
      acc += b2f(Qs[pp * 16 + c]) * b2f(Ks[pp * 16 + d]);
  }
  atomicAdd(&logits[((b * NHEADS + h) * 16 + c) * 16 + d], acc);
}

// ============ softmax with norm (from raw ssq) + temperature scaling ============
__global__ __launch_bounds__(256)
void softmax_k(const float* __restrict__ logits, const float* __restrict__ ssq,
               const float* __restrict__ temp, float* __restrict__ attn) {
  int t0 = blockIdx.x * 256 + threadIdx.x;
  if (t0 >= NB * 96) return;
  int b = t0 / 96, c96 = t0 % 96;
  int h = c96 >> 4, c = c96 & 15;
  float iq = 1.f / fmaxf(sqrtf(ssq[b * 96 + c96]), 1e-12f);
  float tp = temp[h];
  const float* lp = logits + ((b * NHEADS + h) * 16 + c) * 16;
  const float* sk = ssq + NB * 96 + b * 96 + h * 16;
  float s[16], mx = -3.4e38f;
#pragma unroll
  for (int d = 0; d < 16; ++d) {
    float ik = 1.f / fmaxf(sqrtf(sk[d]), 1e-12f);
    float l = lp[d] * iq * ik * tp;
    s[d] = l; mx = fmaxf(mx, l);
  }
  float sum = 0.f;
#pragma unroll
  for (int d = 0; d < 16; ++d) { s[d] = __expf(s[d] - mx); sum += s[d]; }
  float rr = 1.f / sum;
  float* ap = attn + ((b * NHEADS + h) * 16 + c) * 16;
#pragma unroll
  for (int d = 0; d < 16; ++d) ap[d] = s[d] * rr;
}

// ============ W'[b] = Wproj * blockdiag(attn_b): (192 x 96) bf16 per batch ============
__global__ __launch_bounds__(256)
void wattn_k(const float* __restrict__ wproj, const float* __restrict__ attn,
             u16* __restrict__ Wp) {
  int b = blockIdx.x, t = threadIdx.x;
  __shared__ float at[1536];
  for (int i = t; i < 1536; i += 256) at[i] = attn[b * 1536 + i];
  __syncthreads();
  for (int i = t; i < 192 * 96; i += 256) {
    int oc = i / 96, e = i % 96;
    int h = e >> 4, d = e & 15;
    float s = 0.f;
#pragma unroll
    for (int c = 0; c < 16; ++c)
      s += wproj[oc * 96 + h * 16 + c] * at[(h * 16 + c) * 16 + d];
    Wp[(long)b * 18432 + i] = f2b(s);
  }
}

// ============ final: out = [W'_b | Wpos] * [v; x; y]; NCHW fp32 out ============
__global__ __launch_bounds__(256)
void final_k(const u16* __restrict__ Wp, const u16* __restrict__ wpos_b,
             const u16* __restrict__ v, const u16* __restrict__ xb,
             const u16* __restrict__ yb, float* __restrict__ out) {
  int t = threadIdx.x, w = t >> 6, lane = t & 63;
  int q = lane >> 4, l15 = lane & 15;
  long n0 = (long)blockIdx.x * 64;
  long b = n0 >> 14; int ni0 = (int)(n0 & 16383);
  f4_t acc[3][4] = {};
  const u16* Ab0 = Wp + b * 18432;
#pragma unroll
  for (int kc = 0; kc < 9; ++kc) {
    const u16 *Asrc, *Bsrc; int astr, koff, gB;
    if (kc < 3)      { Asrc = Ab0;    astr = 96;  koff = kc * 32;            Bsrc = v;  gB = kc * 4 + q; }
    else if (kc < 6) { Asrc = wpos_b; astr = 192; koff = (kc - 3) * 32;      Bsrc = xb; gB = (kc - 3) * 4 + q; }
    else             { Asrc = wpos_b; astr = 192; koff = 96 + (kc - 6) * 32; Bsrc = yb; gB = (kc - 6) * 4 + q; }
    bf8_t af[3], bfr[4];
#pragma unroll
    for (int mf = 0; mf < 3; ++mf)
      af[mf] = *(const bf8_t*)(Asrc + (w * 48 + mf * 16 + l15) * astr + koff + q * 8);
#pragma unroll
    for (int nf = 0; nf < 4; ++nf)
      bfr[nf] = *(const bf8_t*)(Bsrc + ((long)gB * BT + n0 + nf * 16 + l15) * 8);
#pragma unroll
    for (int mf = 0; mf < 3; ++mf)
#pragma unroll
      for (int nf = 0; nf < 4; ++nf)
        acc[mf][nf] = MFMA(af[mf], bfr[nf], acc[mf][nf]);
  }
#pragma unroll
  for (int mf = 0; mf < 3; ++mf)
#pragma unroll
    for (int nf = 0; nf < 4; ++nf)
#pragma unroll
      for (int rg = 0; rg < 4; ++rg) {
        int oc = w * 48 + mf * 16 + q * 4 + rg;
        out[(b * 192 + oc) * (long)NSP + ni0 + nf * 16 + l15] = acc[mf][nf][rg];
      }
}

extern "C" void kernel_launch(void* const* d_in, const int* in_sizes, int n_in,
                              void* d_out, int out_size, void* d_ws, size_t ws_size,
                              hipStream_t stream) {
  const float* x     = (const float*)d_in[0];
  const float* y     = (const float*)d_in[1];
  const float* wpos  = (const float*)d_in[2];
  const float* wqv   = (const float*)d_in[3];
  const float* wqvd  = (const float*)d_in[4];
  const float* wkv   = (const float*)d_in[5];
  const float* wkvd  = (const float*)d_in[6];
  const float* wproj = (const float*)d_in[7];
  const float* wfuse = (const float*)d_in[8];
  const float* bfuse = (const float*)d_in[9];
  const float* temp  = (const float*)d_in[10];
  float* out = (float*)d_out;
  char*  ws  = (char*)d_ws;

  u16*   xb     = (u16*)(ws);                  // [12][BT][8]
  u16*   yb     = (u16*)(ws + 25165824);       // [12][BT][8]
  u16*   qL     = (u16*)(ws + 50331648);       // q lo-96 [12][BT][8]
  u16*   kL     = (u16*)(ws + 75497472);       // k lo-96 [12][BT][8]
  u16*   fin    = (u16*)(ws + 100663296);      // fuse in [24][BT][8]
  u16*   v      = (u16*)(ws + 150994944);      // [12][BT][8]
  u16*   wqv_b  = (u16*)(ws + 176160768);
  u16*   wkv_b  = (u16*)(ws + 176197632);
  u16*   wpos_b = (u16*)(ws + 176234496);
  u16*   wfA    = (u16*)(ws + 176308224);
  u16*   Wp     = (u16*)(ws + 176640000);
  float* ssq    = (float*)(ws + 176934912);
  float* logits = (float*)(ws + 176941056);
  float* attn   = (float*)(ws + 176990208);

  // d_out doubles as bf16 scratch for the two 1x1-conv outputs (dead after dw)
  u16* qv0 = (u16*)d_out;                       // [24][BT][8]
  u16* kv0 = (u16*)d_out + (size_t)24 * BT * 8; // [24][BT][8]

  dim3 blk(256);
  pack_w_k<<<648, blk, 0, stream>>>(wqv, wkv, wpos, wfuse, wqv_b, wkv_b, wpos_b, wfA);
  tcast_k<<<dim3(2048, 2), blk, 0, stream>>>(x, y, xb, yb);
  conv1x1_k<<<2048, blk, 0, stream>>>(xb, wqv_b, qv0);
  conv1x1_k<<<2048, blk, 0, stream>>>(yb, wkv_b, kv0);
  dw_k<<<dim3(6144, 2), blk, 0, stream>>>(qv0, kv0, wqvd, wkvd, qL, kL, fin);
  hipMemsetAsync(ssq, 0, 6144 + 49152, stream);  // ssq + logits (contiguous)
  fuse_k<<<512, dim3(512), 0, stream>>>(fin, wfA, bfuse, v);
  ssq_k<<<dim3(12, 16, 4), blk, 0, stream>>>(qL, kL, ssq);
  qk_k<<<dim3(32, NHEADS, NB), blk, 0, stream>>>(qL, kL, logits);
  softmax_k<<<3, blk, 0, stream>>>(logits, ssq, temp, attn);
  wattn_k<<<NB, blk, 0, stream>>>(wproj, attn, Wp);
  final_k<<<2048, blk, 0, stream>>>(Wp, wpos_b, v, xb, yb, out);
}

// Round 8
// 469.228 us; speedup vs baseline: 1.1627x; 1.0203x over previous
//
#include <hip/hip_runtime.h>
#include <math.h>

#define NB 8
#define NSP 16384   // 128*128
#define NHEADS 6
#define BT ((long)NB * NSP)   // 131072 pixels total

typedef __attribute__((ext_vector_type(8))) short bf8_t;   // 8 bf16 (4 VGPR)
typedef __attribute__((ext_vector_type(4))) float f4_t;    // MFMA accumulator
typedef unsigned short u16;

#define MFMA(A,B,C) __builtin_amdgcn_mfma_f32_16x16x32_bf16((A),(B),(C),0,0,0)

__device__ __forceinline__ u16 f2b(float f) {  // fp32 -> bf16 RNE
  union { float f; unsigned u; } v; v.f = f;
  unsigned r = v.u + 0x7FFFu + ((v.u >> 16) & 1u);
  return (u16)(r >> 16);
}
__device__ __forceinline__ float b2f(u16 h) {
  union { unsigned u; float f; } v; v.u = ((unsigned)h) << 16; return v.f;
}

// All activation tensors are chunk-major: [g8 chunk][B*N pixels][8 ch] bf16.
// xb/yb/qL/kL/v: 12 chunks. fin (fuse input, 192 ch): 24 chunks
//   (gf 0..11 = kv hi channels 96..191, gf 12..23 = qv hi channels 96..191).

// ============ pack weights to bf16 (+ fuse-weight permutation) ============
// wfA slot kc = c6*9 + tap (tap-INNER iteration order in fuse_k)
__global__ __launch_bounds__(256)
void pack_w_k(const float* __restrict__ wqv, const float* __restrict__ wkv,
              const float* __restrict__ wpos, const float* __restrict__ wfuse,
              u16* __restrict__ wqv_b, u16* __restrict__ wkv_b,
              u16* __restrict__ wpos_b, u16* __restrict__ wfA) {
  int i = blockIdx.x * 256 + threadIdx.x;
  if (i < 18432) { wqv_b[i] = f2b(wqv[i]); wkv_b[i] = f2b(wkv[i]); }
  if (i < 36864) wpos_b[i] = f2b(wpos[i]);
  if (i < 165888) {
    int kl = i & 31; int rest = i >> 5;
    int oc = rest % 96, kc = rest / 96;
    int c6 = kc / 9, tap = kc % 9;
    int icf = c6 * 32 + kl;
    wfA[i] = f2b(wfuse[(oc * 192 + icf) * 9 + tap]);
  }
}

// ============ transpose-cast x,y: (B,96,N) fp32 -> chunk-major bf16 ============
__global__ __launch_bounds__(256)
void tcast_k(const float* __restrict__ x, const float* __restrict__ y,
             u16* __restrict__ xb, u16* __restrict__ yb) {
  const float* src = blockIdx.y ? y : x;
  u16* dst = blockIdx.y ? yb : xb;
  int t = threadIdx.x;
  long n  = (long)blockIdx.x * 64 + (t & 63);
  long b  = n >> 14; long ni = n & 16383;
  int c8b = t >> 6;                 // 0..3
  for (int i = 0; i < 3; ++i) {
    int c8 = c8b + i * 4;           // 0..11
    bf8_t pk;
#pragma unroll
    for (int j = 0; j < 8; ++j)
      pk[j] = (short)f2b(src[(b * 96 + c8 * 8 + j) * NSP + ni]);
    *(bf8_t*)(dst + ((long)c8 * BT + n) * 8) = pk;
  }
}

// ============ conv1x1 MFMA: 192oc x 64n tile; in/out chunk-major ============
__global__ __launch_bounds__(256)
void conv1x1_k(const u16* __restrict__ Bx, const u16* __restrict__ A,
               u16* __restrict__ out) {
  int t = threadIdx.x, w = t >> 6, lane = t & 63;
  int q = lane >> 4, l15 = lane & 15;
  long n0 = (long)blockIdx.x * 64;
  f4_t acc[3][4] = {};
#pragma unroll
  for (int kc = 0; kc < 3; ++kc) {
    bf8_t af[3], bfr[4];
#pragma unroll
    for (int mf = 0; mf < 3; ++mf)
      af[mf] = *(const bf8_t*)(A + (w * 48 + mf * 16 + l15) * 96 + kc * 32 + q * 8);
#pragma unroll
    for (int nf = 0; nf < 4; ++nf)
      bfr[nf] = *(const bf8_t*)(Bx + ((long)(kc * 4 + q) * BT + n0 + nf * 16 + l15) * 8);
#pragma unroll
    for (int mf = 0; mf < 3; ++mf)
#pragma unroll
      for (int nf = 0; nf < 4; ++nf)
        acc[mf][nf] = MFMA(af[mf], bfr[nf], acc[mf][nf]);
  }
#pragma unroll
  for (int mf = 0; mf < 3; ++mf)
#pragma unroll
    for (int nf = 0; nf < 4; ++nf) {
      union { u16 us[4]; uint2 v; } pk;
#pragma unroll
      for (int r = 0; r < 4; ++r) pk.us[r] = f2b(acc[mf][nf][r]);
      long n = n0 + nf * 16 + l15;
      int g = w * 6 + mf * 2 + (q >> 1);     // oc chunk
      *(uint2*)(out + ((long)g * BT + n) * 8 + (q & 1) * 4) = pk.v;
    }
}

// ============ depthwise 3x3, chunk-major: wave = one g, 4 output rows/block ============
// 6 input rows -> 4 output rows (1.5x halo vs 3x); rolling acc completion.
// ssq for lo-96 channels fused into the store epilogue (ssq_k eliminated).
__global__ __launch_bounds__(256)
void dw_k(const u16* __restrict__ qv0, const u16* __restrict__ kv0,
          const float* __restrict__ wqvd, const float* __restrict__ wkvd,
          u16* __restrict__ qL, u16* __restrict__ kL, u16* __restrict__ fin,
          float* __restrict__ ssq) {
  int t = threadIdx.x;
  int sel = blockIdx.y;
  int bx = blockIdx.x;              // 0..1535
  int gq = bx % 6;                  // g-quad
  int rowid = bx / 6;               // 0..255
  long b = rowid >> 5; int rg = rowid & 31;
  int r0 = rg * 4;                  // first output row
  int wv = __builtin_amdgcn_readfirstlane(t >> 6);
  int g = gq * 4 + wv;              // 0..23, wave-uniform
  int l = t & 63;
  int c0 = l * 2;                   // first of 2 px

  const u16* src  = sel ? kv0 : qv0;
  const float* wd = sel ? wkvd : wqvd;

  float wgt[8][9];
#pragma unroll
  for (int cc = 0; cc < 8; ++cc)
#pragma unroll
    for (int tp = 0; tp < 9; ++tp)
      wgt[cc][tp] = wd[g * 72 + cc * 9 + tp];

  const u16* sg = src + (long)g * BT * 8;   // chunk base
  u16* dst; long gi;
  if (g < 12) { dst = sel ? kL : qL; gi = g; }
  else        { dst = fin; gi = sel ? (g - 12) : g; }  // kv hi -> gf 0..11, qv hi -> gf 12..23
  u16* dpb = dst + (gi * BT + (b << 14)) * 8;

  float acc[4][2][8] = {};
  float ssl[8] = {};
#pragma unroll
  for (int j = 0; j < 6; ++j) {             // input row r0-1+j
    int rr = r0 - 1 + j;
    if ((unsigned)rr < 128u) {              // block-uniform
      long nb = (b << 14) + ((long)rr << 7);
      float xq[4][8];
#pragma unroll
      for (int jj = 0; jj < 4; ++jj) {
        int col = c0 - 1 + jj;
        uint4 cv = make_uint4(0u, 0u, 0u, 0u);
        if ((unsigned)col < 128u)
          cv = *(const uint4*)(sg + (nb + col) * 8);
        const unsigned* cu = (const unsigned*)&cv;
#pragma unroll
        for (int k = 0; k < 4; ++k) {
          union { unsigned u; float f; } lo, hi;
          lo.u = cu[k] << 16; hi.u = cu[k] & 0xFFFF0000u;
          xq[jj][2 * k] = lo.f; xq[jj][2 * k + 1] = hi.f;
        }
      }
#pragma unroll
      for (int i = 0; i < 4; ++i) {         // output rows this input feeds
        if (i > j || i + 2 < j) continue;
        int tr = j - i;                     // tap row 0..2
#pragma unroll
        for (int dx = 0; dx < 3; ++dx) {
          int tp = tr * 3 + dx;
#pragma unroll
          for (int px = 0; px < 2; ++px)
#pragma unroll
            for (int cc = 0; cc < 8; ++cc)
              acc[i][px][cc] += wgt[cc][tp] * xq[px + dx][cc];
        }
      }
    }
    if (j >= 2) {                           // output row j-2 complete -> store
      int i = j - 2;
      u16* dp = dpb + ((((long)(r0 + i)) << 7) + c0) * 8;
#pragma unroll
      for (int px = 0; px < 2; ++px) {
        union { u16 us[8]; uint4 v; } pk;
#pragma unroll
        for (int cc = 0; cc < 8; ++cc) pk.us[cc] = f2b(acc[i][px][cc]);
        *(uint4*)(dp + px * 8) = pk.v;
        if (g < 12) {
#pragma unroll
          for (int cc = 0; cc < 8; ++cc) {
            float f = b2f(pk.us[cc]); ssl[cc] += f * f;
          }
        }
      }
    }
  }
  if (g < 12) {                             // fused ssq reduction
#pragma unroll
    for (int off = 32; off; off >>= 1)
#pragma unroll
      for (int cc = 0; cc < 8; ++cc) ssl[cc] += __shfl_down(ssl[cc], off);
    if (l == 0)
#pragma unroll
      for (int cc = 0; cc < 8; ++cc)
        atomicAdd(&ssq[(sel * NB + (int)b) * 96 + g * 8 + cc], ssl[cc]);
  }
}

// ============ fuse 3x3 implicit GEMM: v = Wf(96x1728)*im2col + bias ============
// 512 threads / 8 waves / 256 px per block; 2 weight chunks staged per phase
// (LDS double-buffer, 192 padded rows of 36 u16); one barrier per 2 kc.
__global__ __launch_bounds__(512)
void fuse_k(const u16* __restrict__ fin, const u16* __restrict__ wfA,
            const float* __restrict__ bfuse, u16* __restrict__ vout) {
  __shared__ __align__(16) u16 AL[2][192 * 36];
  int t = threadIdx.x, w = t >> 6, lane = t & 63;
  int q = lane >> 4, l15 = lane & 15;
  int bid = (int)blockIdx.x;
  bid = (bid & 7) * 64 + (bid >> 3);     // XCD swizzle (512 blocks, 1 image/XCD)
  long n0 = (long)bid * 256;
  long b = n0 >> 14; int nimg0 = (int)(n0 & 16383);

  f4_t acc[6][2];
#pragma unroll
  for (int mf = 0; mf < 6; ++mf) {
#pragma unroll
    for (int rg = 0; rg < 4; ++rg) {
      float bv = bfuse[mf * 16 + q * 4 + rg];
      acc[mf][0][rg] = bv; acc[mf][1][rg] = bv;
    }
  }
  int ni_[2], r_[2], pw_[2];
#pragma unroll
  for (int nf = 0; nf < 2; ++nf) {
    ni_[nf] = nimg0 + w * 32 + nf * 16 + l15;
    r_[nf] = ni_[nf] >> 7; pw_[nf] = ni_[nf] & 127;
  }
  // stage chunks 0,1 (768 f4_t; 192 rows of 32 u16 -> padded stride 36)
  for (int i = t; i < 768; i += 512)
    *(f4_t*)(&AL[0][(i >> 2) * 36 + (i & 3) * 8]) = *(const f4_t*)(wfA + i * 8);
  __syncthreads();

  for (int kc2 = 0; kc2 < 27; ++kc2) {
    int cur = kc2 & 1;
    if (kc2 < 26) {
      const u16* srcw = wfA + (kc2 + 1) * 6144;
      for (int i = t; i < 768; i += 512)
        *(f4_t*)(&AL[cur ^ 1][(i >> 2) * 36 + (i & 3) * 8]) = *(const f4_t*)(srcw + i * 8);
    }
#pragma unroll
    for (int h = 0; h < 2; ++h) {
      int kc = kc2 * 2 + h;
      int c6 = kc / 9, tap = kc % 9;
      int dy = tap / 3 - 1, dx = tap % 3 - 1;
      const u16* src = fin + (long)(c6 * 4 + q) * BT * 8;
      bf8_t bfr[2];
#pragma unroll
      for (int nf = 0; nf < 2; ++nf) {
        bf8_t v = {0,0,0,0,0,0,0,0};
        int rr = r_[nf] + dy, cc = pw_[nf] + dx;
        if ((unsigned)rr < 128u && (unsigned)cc < 128u)
          v = *(const bf8_t*)(src + ((b << 14) + (long)ni_[nf] + dy * 128 + dx) * 8);
        bfr[nf] = v;
      }
      bf8_t af[6];
#pragma unroll
      for (int mf = 0; mf < 6; ++mf)
        af[mf] = *(const bf8_t*)(&AL[cur][(h * 96 + mf * 16 + l15) * 36 + q * 8]);
#pragma unroll
      for (int mf = 0; mf < 6; ++mf) {
        acc[mf][0] = MFMA(af[mf], bfr[0], acc[mf][0]);
        acc[mf][1] = MFMA(af[mf], bfr[1], acc[mf][1]);
      }
    }
    __syncthreads();
  }
#pragma unroll
  for (int mf = 0; mf < 6; ++mf)
#pragma unroll
    for (int nf = 0; nf < 2; ++nf) {
      union { u16 us[4]; uint2 v; } pk;
#pragma unroll
      for (int rg = 0; rg < 4; ++rg) pk.us[rg] = f2b(acc[mf][nf][rg]);
      long n = n0 + w * 32 + nf * 16 + l15;
      int gg = mf * 2 + (q >> 1);
      *(uint2*)(vout + ((long)gg * BT + n) * 8 + (q & 1) * 4) = pk.v;
    }
}

// ============ QK^T: logits[b,h,c,d] = sum_n q[n][h16+c] k[n][h16+d] (raw) ============
__global__ __launch_bounds__(256)
void qk_k(const u16* __restrict__ qL, const u16* __restrict__ kL,
          float* __restrict__ logits) {
  int s = blockIdx.x, h = blockIdx.y, b = blockIdx.z;
  int t = threadIdx.x, c = t >> 4, d = t & 15;
  __shared__ u16 Qs[64 * 16], Ks[64 * 16];
  float acc = 0.f;
  int p = t >> 2, c4 = (t & 3) * 4;
  int ch2 = 2 * h + (c4 >> 3), e = c4 & 7;
  long cb = (long)ch2 * BT + (b << 14) + s * 512;
  for (int it = 0; it < 8; ++it) {
    __syncthreads();
    long a = (cb + it * 64 + p) * 8 + e;
    *(uint2*)(&Qs[p * 16 + c4]) = *(const uint2*)(qL + a);
    *(uint2*)(&Ks[p * 16 + c4]) = *(const uint2*)(kL + a);
    __syncthreads();
#pragma unroll 8
    for (int pp = 0; pp < 64; ++pp)
      acc += b2f(Qs[pp * 16 + c]) * b2f(Ks[pp * 16 + d]);
  }
  atomicAdd(&logits[((b * NHEADS + h) * 16 + c) * 16 + d], acc);
}

// ============ softmax with norm (from raw ssq) + temperature scaling ============
__global__ __launch_bounds__(256)
void softmax_k(const float* __restrict__ logits, const float* __restrict__ ssq,
               const float* __restrict__ temp, float* __restrict__ attn) {
  int t0 = blockIdx.x * 256 + threadIdx.x;
  if (t0 >= NB * 96) return;
  int b = t0 / 96, c96 = t0 % 96;
  int h = c96 >> 4, c = c96 & 15;
  float iq = 1.f / fmaxf(sqrtf(ssq[b * 96 + c96]), 1e-12f);
  float tp = temp[h];
  const float* lp = logits + ((b * NHEADS + h) * 16 + c) * 16;
  const float* sk = ssq + NB * 96 + b * 96 + h * 16;
  float s[16], mx = -3.4e38f;
#pragma unroll
  for (int d = 0; d < 16; ++d) {
    float ik = 1.f / fmaxf(sqrtf(sk[d]), 1e-12f);
    float l = lp[d] * iq * ik * tp;
    s[d] = l; mx = fmaxf(mx, l);
  }
  float sum = 0.f;
#pragma unroll
  for (int d = 0; d < 16; ++d) { s[d] = __expf(s[d] - mx); sum += s[d]; }
  float rr = 1.f / sum;
  float* ap = attn + ((b * NHEADS + h) * 16 + c) * 16;
#pragma unroll
  for (int d = 0; d < 16; ++d) ap[d] = s[d] * rr;
}

// ============ W'[b] = Wproj * blockdiag(attn_b): (192 x 96) bf16 per batch ============
__global__ __launch_bounds__(256)
void wattn_k(const float* __restrict__ wproj, const float* __restrict__ attn,
             u16* __restrict__ Wp) {
  int b = blockIdx.x, t = threadIdx.x;
  __shared__ float at[1536];
  for (int i = t; i < 1536; i += 256) at[i] = attn[b * 1536 + i];
  __syncthreads();
  for (int i = t; i < 192 * 96; i += 256) {
    int oc = i / 96, e = i % 96;
    int h = e >> 4, d = e & 15;
    float s = 0.f;
#pragma unroll
    for (int c = 0; c < 16; ++c)
      s += wproj[oc * 96 + h * 16 + c] * at[(h * 16 + c) * 16 + d];
    Wp[(long)b * 18432 + i] = f2b(s);
  }
}

// ============ final: out = [W'_b | Wpos] * [v; x; y]; NCHW fp32 out ============
__global__ __launch_bounds__(256)
void final_k(const u16* __restrict__ Wp, const u16* __restrict__ wpos_b,
             const u16* __restrict__ v, const u16* __restrict__ xb,
             const u16* __restrict__ yb, float* __restrict__ out) {
  int t = threadIdx.x, w = t >> 6, lane = t & 63;
  int q = lane >> 4, l15 = lane & 15;
  long n0 = (long)blockIdx.x * 64;
  long b = n0 >> 14; int ni0 = (int)(n0 & 16383);
  f4_t acc[3][4] = {};
  const u16* Ab0 = Wp + b * 18432;
#pragma unroll
  for (int kc = 0; kc < 9; ++kc) {
    const u16 *Asrc, *Bsrc; int astr, koff, gB;
    if (kc < 3)      { Asrc = Ab0;    astr = 96;  koff = kc * 32;            Bsrc = v;  gB = kc * 4 + q; }
    else if (kc < 6) { Asrc = wpos_b; astr = 192; koff = (kc - 3) * 32;      Bsrc = xb; gB = (kc - 3) * 4 + q; }
    else             { Asrc = wpos_b; astr = 192; koff = 96 + (kc - 6) * 32; Bsrc = yb; gB = (kc - 6) * 4 + q; }
    bf8_t af[3], bfr[4];
#pragma unroll
    for (int mf = 0; mf < 3; ++mf)
      af[mf] = *(const bf8_t*)(Asrc + (w * 48 + mf * 16 + l15) * astr + koff + q * 8);
#pragma unroll
    for (int nf = 0; nf < 4; ++nf)
      bfr[nf] = *(const bf8_t*)(Bsrc + ((long)gB * BT + n0 + nf * 16 + l15) * 8);
#pragma unroll
    for (int mf = 0; mf < 3; ++mf)
#pragma unroll
      for (int nf = 0; nf < 4; ++nf)
        acc[mf][nf] = MFMA(af[mf], bfr[nf], acc[mf][nf]);
  }
#pragma unroll
  for (int mf = 0; mf < 3; ++mf)
#pragma unroll
    for (int nf = 0; nf < 4; ++nf)
#pragma unroll
      for (int rg = 0; rg < 4; ++rg) {
        int oc = w * 48 + mf * 16 + q * 4 + rg;
        out[(b * 192 + oc) * (long)NSP + ni0 + nf * 16 + l15] = acc[mf][nf][rg];
      }
}

extern "C" void kernel_launch(void* const* d_in, const int* in_sizes, int n_in,
                              void* d_out, int out_size, void* d_ws, size_t ws_size,
                              hipStream_t stream) {
  const float* x     = (const float*)d_in[0];
  const float* y     = (const float*)d_in[1];
  const float* wpos  = (const float*)d_in[2];
  const float* wqv   = (const float*)d_in[3];
  const float* wqvd  = (const float*)d_in[4];
  const float* wkv   = (const float*)d_in[5];
  const float* wkvd  = (const float*)d_in[6];
  const float* wproj = (const float*)d_in[7];
  const float* wfuse = (const float*)d_in[8];
  const float* bfuse = (const float*)d_in[9];
  const float* temp  = (const float*)d_in[10];
  float* out = (float*)d_out;
  char*  ws  = (char*)d_ws;

  u16*   xb     = (u16*)(ws);                  // [12][BT][8]
  u16*   yb     = (u16*)(ws + 25165824);       // [12][BT][8]
  u16*   qL     = (u16*)(ws + 50331648);       // q lo-96 [12][BT][8]
  u16*   kL     = (u16*)(ws + 75497472);       // k lo-96 [12][BT][8]
  u16*   fin    = (u16*)(ws + 100663296);      // fuse in [24][BT][8]
  u16*   v      = (u16*)(ws + 150994944);      // [12][BT][8]
  u16*   wqv_b  = (u16*)(ws + 176160768);
  u16*   wkv_b  = (u16*)(ws + 176197632);
  u16*   wpos_b = (u16*)(ws + 176234496);
  u16*   wfA    = (u16*)(ws + 176308224);
  u16*   Wp     = (u16*)(ws + 176640000);
  float* ssq    = (float*)(ws + 176934912);
  float* logits = (float*)(ws + 176941056);
  float* attn   = (float*)(ws + 176990208);

  // d_out doubles as bf16 scratch for the two 1x1-conv outputs (dead after dw)
  u16* qv0 = (u16*)d_out;                       // [24][BT][8]
  u16* kv0 = (u16*)d_out + (size_t)24 * BT * 8; // [24][BT][8]

  dim3 blk(256);
  pack_w_k<<<648, blk, 0, stream>>>(wqv, wkv, wpos, wfuse, wqv_b, wkv_b, wpos_b, wfA);
  tcast_k<<<dim3(2048, 2), blk, 0, stream>>>(x, y, xb, yb);
  conv1x1_k<<<2048, blk, 0, stream>>>(xb, wqv_b, qv0);
  conv1x1_k<<<2048, blk, 0, stream>>>(yb, wkv_b, kv0);
  hipMemsetAsync(ssq, 0, 6144 + 49152, stream);  // ssq + logits (contiguous)
  dw_k<<<dim3(1536, 2), blk, 0, stream>>>(qv0, kv0, wqvd, wkvd, qL, kL, fin, ssq);
  fuse_k<<<512, dim3(512), 0, stream>>>(fin, wfA, bfuse, v);
  qk_k<<<dim3(32, NHEADS, NB), blk, 0, stream>>>(qL, kL, logits);
  softmax_k<<<3, blk, 0, stream>>>(logits, ssq, temp, attn);
  wattn_k<<<NB, blk, 0, stream>>>(wproj, attn, Wp);
  final_k<<<2048, blk, 0, stream>>>(Wp, wpos_b, v, xb, yb, out);
}